// Round 5
// baseline (551.501 us; speedup 1.0000x reference)
//
#include <hip/hip_runtime.h>

typedef unsigned short u16;
typedef unsigned int u32;
typedef __attribute__((ext_vector_type(8))) short short8;
typedef __attribute__((ext_vector_type(4))) float f32x4;
typedef __attribute__((ext_vector_type(4))) u32 u32x4;

__device__ __forceinline__ float bf2f(u16 u){ u32 x = ((u32)u)<<16; float f; __builtin_memcpy(&f,&x,4); return f; }
__device__ __forceinline__ u16 f2bf(float f){ u32 u; __builtin_memcpy(&u,&f,4); u32 r = (u + 0x7fffu + ((u>>16)&1u))>>16; return (u16)r; }

__device__ __forceinline__ float wsum64(float v){
  #pragma unroll
  for (int m=32;m>=1;m>>=1) v += __shfl_xor(v,m,64);
  return v;
}
__device__ __forceinline__ float wsum32(float v){
  #pragma unroll
  for (int m=16;m>=1;m>>=1) v += __shfl_xor(v,m,64);
  return v;
}

struct WPtrs { const float* s[10]; u16* d[10]; };

// all 10 weight transposes in ONE dispatch (grid 640)
__global__ __launch_bounds__(256) void kconv_all(WPtrs wp){
  int mid = blockIdx.x>>6;
  int t = (blockIdx.x&63)*256 + threadIdx.x;
  int n = t>>7, k = t&127;
  wp.d[mid][n*128+k] = f2bf(wp.s[mid][k*128+n]);
}

// one wave per pair (i,j): dist->rbf->LN->dist_bias; shared edge LN -> zln + exp(bias) in C-frag layout
__global__ __launch_bounds__(256) void kprep(
    const float* __restrict__ ee, const float* __restrict__ coords,
    const float* __restrict__ w1, const float* __restrict__ rg, const float* __restrict__ rbta,
    const float* __restrict__ w2, const float* __restrict__ g3, const float* __restrict__ b3,
    const float* __restrict__ w3, const float* __restrict__ gs, const float* __restrict__ bs,
    const float* __restrict__ mask,
    u16* __restrict__ zln, u16* __restrict__ ebx0, u16* __restrict__ ebxT,
    float* __restrict__ maskE)
{
  int wid = (blockIdx.x*256 + threadIdx.x)>>6;
  int lane = threadIdx.x & 63;
  int i = wid>>8, j = wid&255;
  float dx = coords[i*3+0]-coords[j*3+0];
  float dy = coords[i*3+1]-coords[j*3+1];
  float dz = coords[i*3+2]-coords[j*3+2];
  float dist = sqrtf(dx*dx+dy*dy+dz*dz+1e-12f);
  float rbv = 0.f;
  if (lane<39){ float t = (dist-(0.325f+0.125f*(float)lane))*8.210526315789474f; rbv = __expf(-t*t); }
  int c = lane&31;
  float hacc = 0.f;
  #pragma unroll
  for (int r=0;r<39;r++){ float rv = __shfl(rbv,r,64); hacc = fmaf(rv, w1[r*32+c], hacc); }
  float mu = wsum32(hacc)*(1.f/32.f);
  float vr = wsum32(hacc*hacc)*(1.f/32.f) - mu*mu;
  float hn = (hacc-mu)*rsqrtf(vr+1e-5f)*rg[c]+rbta[c];
  float db0 = wsum32(hn*w2[c*4+0]);
  float db1 = wsum32(hn*w2[c*4+1]);
  float db2 = wsum32(hn*w2[c*4+2]);
  float db3 = wsum32(hn*w2[c*4+3]);
  int c0 = lane*2, c1 = lane*2+1;
  float x0 = ee[(size_t)wid*128+c0], x1 = ee[(size_t)wid*128+c1];
  float m2 = wsum64(x0+x1)*(1.f/128.f);
  float v2 = wsum64(x0*x0+x1*x1)*(1.f/128.f)-m2*m2;
  float rinv = rsqrtf(v2+1e-5f);
  float n0 = (x0-m2)*rinv, n1 = (x1-m2)*rinv;
  u32 pk = (u32)f2bf(n0*gs[c0]+bs[c0]) | ((u32)f2bf(n1*gs[c1]+bs[c1])<<16);
  ((u32*)zln)[(size_t)wid*64+lane] = pk;
  float t0 = n0*g3[c0]+b3[c0], t1 = n1*g3[c1]+b3[c1];
  float th0 = wsum64(t0*w3[c0*4+0]+t1*w3[c1*4+0]);
  float th1 = wsum64(t0*w3[c0*4+1]+t1*w3[c1*4+1]);
  float th2 = wsum64(t0*w3[c0*4+2]+t1*w3[c1*4+2]);
  float th3 = wsum64(t0*w3[c0*4+3]+t1*w3[c1*4+3]);
  if (lane<4){
    float v = (lane==0)?(db0+th0):(lane==1)?(db1+th1):(lane==2)?(db2+th2):(db3+th3);
    u16 ev = f2bf(__expf(v));
    int h = lane;
    ebx0[(((size_t)(h*16+(i>>4))*16+(j>>4))*256) + ((j&15)+((i>>2)&3)*16)*4 + (i&3)] = ev;
    ebxT[(((size_t)(h*16+(j>>4))*16+(i>>4))*256) + ((i&15)+((j>>2)&3)*16)*4 + (j&3)] = ev;
  }
  if (lane==4) maskE[(size_t)j*256+i] = mask[(size_t)wid];
}

// zln[65536,128] @ all 4 W; A staged+fragged ONCE; outputs restaged via LDS, 16B coalesced stores
__global__ __launch_bounds__(256) void kqkvg(const u16* __restrict__ zln, const u16* __restrict__ wT,
                                             u16* __restrict__ Qf, u16* __restrict__ Kf,
                                             u16* __restrict__ Vf, u16* __restrict__ Gm){
  const int m0 = blockIdx.x*128;
  __shared__ u16 A[128*136];
  const int tid = threadIdx.x;
  #pragma unroll
  for (int r=0;r<8;r++){
    int chunk = tid + 256*r;
    int row = chunk>>4, off = (chunk&15)*8;
    *(u32x4*)&A[row*136+off] = *(const u32x4*)&zln[(size_t)(m0+row)*128+off];
  }
  __syncthreads();
  const int w = tid>>6, lane = tid&63, r16 = lane&15, gq = lane>>4;
  short8 a[2][4];
  #pragma unroll
  for (int mt=0;mt<2;mt++)
    #pragma unroll
    for (int ks=0;ks<4;ks++)
      a[mt][ks] = *(const short8*)&A[(w*32+mt*16+r16)*136 + ks*32 + gq*8];
  const int ii = m0>>8, hb = (blockIdx.x&1);
  for (int sel=0; sel<4; sel++){
    f32x4 acc[2][8];
    #pragma unroll
    for (int mt=0;mt<2;mt++)
      #pragma unroll
      for (int nt=0;nt<8;nt++)
        acc[mt][nt] = (f32x4){0.f,0.f,0.f,0.f};
    #pragma unroll
    for (int nt=0;nt<8;nt++){
      short8 bq[4];
      #pragma unroll
      for (int ks=0;ks<4;ks++)
        bq[ks] = *(const short8*)&wT[(size_t)(sel*128+nt*16+r16)*128 + ks*32 + gq*8];
      #pragma unroll
      for (int mt=0;mt<2;mt++)
        #pragma unroll
        for (int ks=0;ks<4;ks++)
          acc[mt][nt] = __builtin_amdgcn_mfma_f32_16x16x32_bf16(a[mt][ks], bq[ks], acc[mt][nt], 0,0,0);
    }
    __syncthreads();   // prior copy-out reads of A complete
    if (sel==2){
      #pragma unroll
      for (int mt=0;mt<2;mt++)
        #pragma unroll
        for (int nt=0;nt<8;nt++)
          #pragma unroll
          for (int reg=0;reg<4;reg++)
            A[(nt*16+r16)*136 + (w*32+mt*16+gq*4+reg)] = f2bf(acc[mt][nt][reg]);
    } else {
      #pragma unroll
      for (int mt=0;mt<2;mt++)
        #pragma unroll
        for (int nt=0;nt<8;nt++)
          #pragma unroll
          for (int reg=0;reg<4;reg++){
            float v = acc[mt][nt][reg];
            if (sel==3) v = 1.f/(1.f+__expf(-v));
            A[(w*32+mt*16+gq*4+reg)*136 + nt*16+r16] = f2bf(v);
          }
    }
    __syncthreads();
    if (sel==3){
      #pragma unroll
      for (int it=0; it<8; it++){
        int slot = it*256+tid; int row = slot>>4, c8 = (slot&15)*8;
        u32x4 vdat = *(const u32x4*)&A[row*136 + c8];
        *(u32x4*)&Gm[(size_t)(m0+row)*128 + c8] = vdat;
      }
    } else if (sel==2){
      #pragma unroll
      for (int it=0; it<8; it++){
        int slot = it*256+tid; int tile = slot>>6, l = slot&63;
        int hh = tile>>3, j32l = (tile>>1)&3, c16 = tile&1;
        u32x4 vdat = *(const u32x4*)&A[(hh*32 + c16*16 + (l&15))*136 + j32l*32 + (l>>4)*8];
        size_t gidx = ((((size_t)(ii*4+hh)*8 + hb*4 + j32l)*2 + c16)*64 + l)*8;
        *(u32x4*)&Vf[gidx] = vdat;
      }
    } else {
      u16* __restrict__ dst = (sel==0)? Qf : Kf;
      #pragma unroll
      for (int it=0; it<8; it++){
        int slot = it*256+tid; int tile = slot>>6, l = slot&63;
        int a8 = tile>>2, hh = tile&3;
        u32x4 vdat = *(const u32x4*)&A[(a8*16 + (l&15))*136 + hh*32 + (l>>4)*8];
        size_t gidx = (((size_t)(ii*4+hh)*16 + hb*8 + a8)*64 + l)*8;
        *(u32x4*)&dst[gidx] = vdat;
      }
    }
  }
}

// attention: grid (i, qhalf); 8 qt per block (halves K/V HBM refetch); og restaged -> 16B stores
__global__ __launch_bounds__(256,4) void kattn(const u16* __restrict__ Qf, const u16* __restrict__ Kf,
                                               const u16* __restrict__ Vf, const u16* __restrict__ ebx,
                                               const float* __restrict__ maskp, u16* __restrict__ og){
  const int i = blockIdx.x, qh = blockIdx.y, tid = threadIdx.x;
  const int h = tid>>6, lane = tid&63, r16 = lane&15, gq = lane>>4;
  __shared__ u16 P[4][16*264];
  __shared__ u16 O[4][16*32];
  u16* Ph = P[h];
  u16* Oh = O[h];
  float pm[16];
  const float* mrow = maskp + (size_t)i*256;
  #pragma unroll
  for (int kt=0;kt<16;kt++){
    float mv = mrow[kt*16+r16];
    pm[kt] = (mv > 0.999f) ? 1.f : 0.f;
  }
  const u16* qhb = Qf + (size_t)(i*4+h)*16*512;
  const u16* khb = Kf + (size_t)(i*4+h)*16*512;
  const u16* vhb = Vf + (size_t)(i*4+h)*16*512;
  const u16* ebt = ebx + (size_t)h*16*16*256;
  for (int qt=qh*8; qt<qh*8+8; qt++){
    short8 aq = *(const short8*)&qhb[qt*512 + lane*8];
    float sums[4] = {0.f,0.f,0.f,0.f};
    #pragma unroll
    for (int half=0;half<2;half++){
      f32x4 s[8];
      #pragma unroll
      for (int kt2=0;kt2<8;kt2++){
        short8 bk = *(const short8*)&khb[(half*8+kt2)*512 + lane*8];
        f32x4 z = {0.f,0.f,0.f,0.f};
        s[kt2] = __builtin_amdgcn_mfma_f32_16x16x32_bf16(aq, bk, z, 0,0,0);
      }
      #pragma unroll
      for (int kt2=0;kt2<8;kt2++){
        int kt = half*8+kt2;
        int kk = kt*16 + r16;
        uint2 er = *(const uint2*)&ebt[((size_t)(qt*16+kt)*64 + lane)*4];
        u16 e4[4]; __builtin_memcpy(e4, &er, 8);
        #pragma unroll
        for (int reg=0;reg<4;reg++){
          float e = __expf(s[kt2][reg]*0.17677669529663687f) * bf2f(e4[reg]) * pm[kt];
          sums[reg] += e;
          Ph[(gq*4+reg)*264 + kk] = f2bf(e);
        }
      }
    }
    #pragma unroll
    for (int reg=0;reg<4;reg++){
      #pragma unroll
      for (int mm=1;mm<=8;mm<<=1) sums[reg] += __shfl_xor(sums[reg],mm,64);
      sums[reg] = 1.f/sums[reg];
    }
    f32x4 o[2]; o[0]=(f32x4){0.f,0.f,0.f,0.f}; o[1]=(f32x4){0.f,0.f,0.f,0.f};
    #pragma unroll
    for (int ks=0;ks<8;ks++){
      short8 ap = *(const short8*)&Ph[r16*264 + ks*32 + gq*8];
      #pragma unroll
      for (int ct=0;ct<2;ct++){
        short8 bv = *(const short8*)&vhb[(ks*2+ct)*512 + lane*8];
        o[ct] = __builtin_amdgcn_mfma_f32_16x16x32_bf16(ap, bv, o[ct], 0,0,0);
      }
    }
    // restage output through LDS: 16B/lane, 64B-aligned global stores
    #pragma unroll
    for (int ct=0;ct<2;ct++)
      #pragma unroll
      for (int reg=0;reg<4;reg++)
        Oh[(gq*4+reg)*32 + ct*16+r16] = f2bf(o[ct][reg]*sums[reg]);
    u32x4 odat = *(const u32x4*)&Oh[(lane>>2)*32 + (lane&3)*8];
    *(u32x4*)&og[((size_t)i*256 + qt*16 + (lane>>2))*128 + h*32 + (lane&3)*8] = odat;
  }
}

// (og*G)[65536,128] @ woT + residual -> out; s-pass: + fused e-LN -> zln (transposed) ; e-pass: transposed scatter
__global__ __launch_bounds__(256) void kproj(const u16* __restrict__ og, const u16* __restrict__ Gm,
                                             const u16* __restrict__ woT,
                                             const float* __restrict__ resid, float* __restrict__ out,
                                             u16* __restrict__ zln, const float* __restrict__ eg,
                                             const float* __restrict__ eb, const int epass){
  const int m0 = blockIdx.x*128;
  __shared__ u16 A[128*136];
  const int tid = threadIdx.x;
  #pragma unroll
  for (int r=0;r<8;r++){
    int chunk = tid + 256*r;
    int row = chunk>>4, off = (chunk&15)*8;
    short8 av = *(const short8*)&og[(size_t)(m0+row)*128+off];
    short8 gv = *(const short8*)&Gm[(size_t)(m0+row)*128+off];
    u16 tmp[8];
    #pragma unroll
    for (int e=0;e<8;e++) tmp[e] = f2bf(bf2f((u16)av[e])*bf2f((u16)gv[e]));
    u32x4 packed; __builtin_memcpy(&packed, tmp, 16);
    *(u32x4*)&A[row*136+off] = packed;
  }
  __syncthreads();
  const int w = tid>>6, lane = tid&63, r16 = lane&15, gq = lane>>4;
  short8 a[2][4];
  #pragma unroll
  for (int mt=0;mt<2;mt++)
    #pragma unroll
    for (int ks=0;ks<4;ks++)
      a[mt][ks] = *(const short8*)&A[(w*32+mt*16+r16)*136 + ks*32 + gq*8];
  f32x4 acc[2][8];
  #pragma unroll
  for (int mt=0;mt<2;mt++)
    #pragma unroll
    for (int nt=0;nt<8;nt++)
      acc[mt][nt] = (f32x4){0.f,0.f,0.f,0.f};
  #pragma unroll
  for (int nt=0;nt<8;nt++){
    short8 bq[4];
    #pragma unroll
    for (int ks=0;ks<4;ks++)
      bq[ks] = *(const short8*)&woT[(size_t)(nt*16+r16)*128 + ks*32 + gq*8];
    #pragma unroll
    for (int mt=0;mt<2;mt++)
      #pragma unroll
      for (int ks=0;ks<4;ks++)
        acc[mt][nt] = __builtin_amdgcn_mfma_f32_16x16x32_bf16(a[mt][ks], bq[ks], acc[mt][nt], 0,0,0);
  }
  if (epass){
    #pragma unroll
    for (int mt=0;mt<2;mt++){
      int mbase = m0+w*32+mt*16+gq*4;
      #pragma unroll
      for (int nt=0;nt<8;nt++){
        int n = nt*16+r16;
        #pragma unroll
        for (int reg=0;reg<4;reg++){
          int m = mbase+reg;
          size_t idx = ((size_t)((m&255)*256+(m>>8)))*128+(size_t)n;
          out[idx] = resid[idx] + acc[mt][nt][reg];
        }
      }
    }
  } else {
    // write out + fused e-LN -> A (normalized bf16), then transposed coalesced copy to zln
    __syncthreads();   // done reading A as input
    #pragma unroll
    for (int mt=0;mt<2;mt++){
      int mbase = m0+w*32+mt*16+gq*4;
      #pragma unroll
      for (int reg=0;reg<4;reg++){
        int m = mbase+reg;
        float s1 = 0.f, s2 = 0.f;
        #pragma unroll
        for (int nt=0;nt<8;nt++){
          int n = nt*16+r16;
          size_t idx = (size_t)m*128+(size_t)n;
          float v = resid[idx] + acc[mt][nt][reg];
          out[idx] = v;
          acc[mt][nt][reg] = v;
          s1 += v; s2 += v*v;
        }
        #pragma unroll
        for (int mm=1;mm<=8;mm<<=1){ s1 += __shfl_xor(s1,mm,64); s2 += __shfl_xor(s2,mm,64); }
        float mean = s1*(1.f/128.f);
        float rinv = rsqrtf(s2*(1.f/128.f)-mean*mean+1e-5f);
        #pragma unroll
        for (int nt=0;nt<8;nt++){
          int n = nt*16+r16;
          A[(m-m0)*136 + n] = f2bf((acc[mt][nt][reg]-mean)*rinv*eg[n]+eb[n]);
        }
      }
    }
    __syncthreads();
    const int i = m0>>8, jb = m0&255;
    #pragma unroll
    for (int it=0; it<8; it++){
      int chunk = it*256+tid;
      int rl = chunk>>4, c8 = (chunk&15)*8;
      u32x4 vdat = *(const u32x4*)&A[rl*136 + c8];
      *(u32x4*)&zln[((size_t)(jb+rl)*256 + i)*128 + c8] = vdat;
    }
  }
}

extern "C" void kernel_launch(void* const* d_in, const int* in_sizes, int n_in,
                              void* d_out, int out_size, void* d_ws, size_t ws_size,
                              hipStream_t stream) {
  const float* ee     = (const float*)d_in[0];
  const float* coords = (const float*)d_in[1];
  const float* mask   = (const float*)d_in[2];
  const float* w1     = (const float*)d_in[3];
  const float* rg     = (const float*)d_in[4];
  const float* rbta   = (const float*)d_in[5];
  const float* w2     = (const float*)d_in[6];
  const float* g3     = (const float*)d_in[7];
  const float* b3     = (const float*)d_in[8];
  const float* w3     = (const float*)d_in[9];
  const float* sln_g  = (const float*)d_in[10];
  const float* sln_b  = (const float*)d_in[11];
  const float* eln_g  = (const float*)d_in[17];
  const float* eln_b  = (const float*)d_in[18];
  float* out = (float*)d_out;
  char* ws = (char*)d_ws;

  u16*   wT_s  = (u16*)(ws + 0);           // 512x128 bf16
  u16*   wT_e  = (u16*)(ws + 131072);
  u16*   woT_s = (u16*)(ws + 262144);      // 128x128 bf16
  u16*   woT_e = (u16*)(ws + 294912);
  u16*   ebx0  = (u16*)(ws + 327680);      // exp(bias) frag [4][16][16][64][4] bf16
  u16*   ebxT  = (u16*)(ws + 851968);
  float* maskE = (float*)(ws + 1376256);   // transposed mask [256][256] f32
  u16*   zln   = (u16*)(ws + 1638400);     // [65536][128] bf16 (reused as og)
  u16*   Qf    = (u16*)(ws + 18415616);
  u16*   Kf    = (u16*)(ws + 35192832);
  u16*   Vf    = (u16*)(ws + 51970048);
  u16*   Gm    = (u16*)(ws + 68747264);

  WPtrs wp;
  for (int s=0;s<4;s++){ wp.s[s] = (const float*)d_in[12+s]; wp.d[s] = wT_s + s*128*128; }
  wp.s[4] = (const float*)d_in[16]; wp.d[4] = woT_s;
  for (int s=0;s<4;s++){ wp.s[5+s] = (const float*)d_in[19+s]; wp.d[5+s] = wT_e + s*128*128; }
  wp.s[9] = (const float*)d_in[23]; wp.d[9] = woT_e;
  kconv_all<<<640,256,0,stream>>>(wp);

  kprep<<<16384,256,0,stream>>>(ee, coords, w1, rg, rbta, w2, g3, b3, w3, sln_g, sln_b,
                                mask, zln, ebx0, ebxT, maskE);

  // ---- starting pass ----
  kqkvg<<<512,256,0,stream>>>(zln, wT_s, Qf, Kf, Vf, Gm);
  kattn<<<dim3(256,2),256,0,stream>>>(Qf, Kf, Vf, ebx0, mask, zln /*og*/);
  kproj<<<512,256,0,stream>>>(zln /*og*/, Gm, woT_s, ee, out, zln, eln_g, eln_b, 0);

  // ---- ending pass (transposed frame; zln already LN'd+transposed by kproj) ----
  kqkvg<<<512,256,0,stream>>>(zln, wT_e, Qf, Kf, Vf, Gm);
  kattn<<<dim3(256,2),256,0,stream>>>(Qf, Kf, Vf, ebxT, maskE, zln /*og*/);
  kproj<<<512,256,0,stream>>>(zln /*og*/, Gm, woT_e, out, out, nullptr, nullptr, nullptr, 1);
}

// Round 7
// 438.570 us; speedup vs baseline: 1.2575x; 1.2575x over previous
//
#include <hip/hip_runtime.h>

typedef unsigned short u16;
typedef unsigned int u32;
typedef __attribute__((ext_vector_type(4))) short short4v;
typedef __attribute__((ext_vector_type(8))) short short8;
typedef __attribute__((ext_vector_type(4))) float f32x4;
typedef __attribute__((ext_vector_type(4))) u32 u32x4;

__device__ __forceinline__ float bf2f(u16 u){ u32 x = ((u32)u)<<16; float f; __builtin_memcpy(&f,&x,4); return f; }
__device__ __forceinline__ u16 f2bf(float f){ u32 u; __builtin_memcpy(&u,&f,4); u32 r = (u + 0x7fffu + ((u>>16)&1u))>>16; return (u16)r; }

__device__ __forceinline__ float wsum64(float v){
  #pragma unroll
  for (int m=32;m>=1;m>>=1) v += __shfl_xor(v,m,64);
  return v;
}
__device__ __forceinline__ float wsum32(float v){
  #pragma unroll
  for (int m=16;m>=1;m>>=1) v += __shfl_xor(v,m,64);
  return v;
}

struct WPtrs { const float* s[10]; u16* d[10]; };

__global__ __launch_bounds__(256) void kconv_all(WPtrs wp){
  int mid = blockIdx.x>>6;
  int t = (blockIdx.x&63)*256 + threadIdx.x;
  int n = t>>7, k = t&127;
  wp.d[mid][n*128+k] = f2bf(wp.s[mid][k*128+n]);
}

// one wave per pair (i,j): dist->rbf->LN->dist_bias; shared edge LN -> zln + exp(bias) in C-frag layout
__global__ __launch_bounds__(256) void kprep(
    const float* __restrict__ ee, const float* __restrict__ coords,
    const float* __restrict__ w1, const float* __restrict__ rg, const float* __restrict__ rbta,
    const float* __restrict__ w2, const float* __restrict__ g3, const float* __restrict__ b3,
    const float* __restrict__ w3, const float* __restrict__ gs, const float* __restrict__ bs,
    const float* __restrict__ mask,
    u16* __restrict__ zln, u16* __restrict__ ebx0, u16* __restrict__ ebxT,
    float* __restrict__ maskE)
{
  int wid = (blockIdx.x*256 + threadIdx.x)>>6;
  int lane = threadIdx.x & 63;
  int i = wid>>8, j = wid&255;
  float dx = coords[i*3+0]-coords[j*3+0];
  float dy = coords[i*3+1]-coords[j*3+1];
  float dz = coords[i*3+2]-coords[j*3+2];
  float dist = sqrtf(dx*dx+dy*dy+dz*dz+1e-12f);
  float rbv = 0.f;
  if (lane<39){ float t = (dist-(0.325f+0.125f*(float)lane))*8.210526315789474f; rbv = __expf(-t*t); }
  int c = lane&31;
  float hacc = 0.f;
  #pragma unroll
  for (int r=0;r<39;r++){ float rv = __shfl(rbv,r,64); hacc = fmaf(rv, w1[r*32+c], hacc); }
  float mu = wsum32(hacc)*(1.f/32.f);
  float vr = wsum32(hacc*hacc)*(1.f/32.f) - mu*mu;
  float hn = (hacc-mu)*rsqrtf(vr+1e-5f)*rg[c]+rbta[c];
  float db0 = wsum32(hn*w2[c*4+0]);
  float db1 = wsum32(hn*w2[c*4+1]);
  float db2 = wsum32(hn*w2[c*4+2]);
  float db3 = wsum32(hn*w2[c*4+3]);
  int c0 = lane*2, c1 = lane*2+1;
  float x0 = ee[(size_t)wid*128+c0], x1 = ee[(size_t)wid*128+c1];
  float m2 = wsum64(x0+x1)*(1.f/128.f);
  float v2 = wsum64(x0*x0+x1*x1)*(1.f/128.f)-m2*m2;
  float rinv = rsqrtf(v2+1e-5f);
  float n0 = (x0-m2)*rinv, n1 = (x1-m2)*rinv;
  u32 pk = (u32)f2bf(n0*gs[c0]+bs[c0]) | ((u32)f2bf(n1*gs[c1]+bs[c1])<<16);
  ((u32*)zln)[(size_t)wid*64+lane] = pk;
  float t0 = n0*g3[c0]+b3[c0], t1 = n1*g3[c1]+b3[c1];
  float th0 = wsum64(t0*w3[c0*4+0]+t1*w3[c1*4+0]);
  float th1 = wsum64(t0*w3[c0*4+1]+t1*w3[c1*4+1]);
  float th2 = wsum64(t0*w3[c0*4+2]+t1*w3[c1*4+2]);
  float th3 = wsum64(t0*w3[c0*4+3]+t1*w3[c1*4+3]);
  if (lane<4){
    float v = (lane==0)?(db0+th0):(lane==1)?(db1+th1):(lane==2)?(db2+th2):(db3+th3);
    u16 ev = f2bf(__expf(v));
    int h = lane;
    ebx0[(((size_t)(h*16+(i>>4))*16+(j>>4))*256) + ((j&15)+((i>>2)&3)*16)*4 + (i&3)] = ev;
    ebxT[(((size_t)(h*16+(j>>4))*16+(i>>4))*256) + ((i&15)+((j>>2)&3)*16)*4 + (j&3)] = ev;
  }
  if (lane==4) maskE[(size_t)j*256+i] = mask[(size_t)wid];
}

// ---- fused QKVG-GEMM + attention + gate, one block per row i, 512 threads ----
// LDS (u16 offsets): Qb@0 pitch36, Kb@9216 pitch36, Vb@18432 pitch268, P@27008+w*4288
#define QB_OFF 0
#define KB_OFF 9216
#define VB_OFF 18432
#define PB_OFF 27008
__global__ __launch_bounds__(512,1) void kfused(const u16* __restrict__ zln, const u16* __restrict__ wT,
                                                const u16* __restrict__ ebx, const float* __restrict__ maskp,
                                                u16* __restrict__ og){
  __shared__ u16 S[61312];
  const int i = blockIdx.x, tid = threadIdx.x;
  const int w = tid>>6, lane = tid&63, r16 = lane&15, gq = lane>>4;
  // phase 0: stage z rows [i*256, i*256+256) -> zbuf pitch 136 (256 rows x 16 chunks = 4096)
  #pragma unroll
  for (int r=0;r<8;r++){
    int chunk = tid + 512*r;
    int row = chunk>>4, off = (chunk&15)*8;
    *(u32x4*)&S[row*136+off] = *(const u32x4*)&zln[((size_t)i*256+row)*128+off];
  }
  __syncthreads();
  // phase 1: per-wave A-fragments (rows w*32..+31)
  short8 a[2][4];
  #pragma unroll
  for (int mt=0;mt<2;mt++)
    #pragma unroll
    for (int ks=0;ks<4;ks++)
      a[mt][ks] = *(const short8*)&S[(w*32+mt*16+r16)*136 + ks*32 + gq*8];
  // mask factors
  float pm[16];
  const float* mrow = maskp + (size_t)i*256;
  #pragma unroll
  for (int kt=0;kt<16;kt++)
    pm[kt] = (mrow[kt*16+r16] > 0.999f) ? 1.f : 0.f;

  u16* Pw = &S[PB_OFF + w*4288];

  for (int h=0; h<4; h++){
    // ---- GEMM phase: Q,K,V,G for head h (registers+global only) ----
    f32x4 accQ[2][2], accK[2][2], accV[2][2], accG[2][2];
    #pragma unroll
    for (int mt=0;mt<2;mt++)
      #pragma unroll
      for (int nt=0;nt<2;nt++){
        accQ[mt][nt]=(f32x4){0,0,0,0}; accK[mt][nt]=(f32x4){0,0,0,0};
        accV[mt][nt]=(f32x4){0,0,0,0}; accG[mt][nt]=(f32x4){0,0,0,0};
      }
    #pragma unroll
    for (int nt=0;nt<2;nt++)
      #pragma unroll
      for (int ks=0;ks<4;ks++){
        short8 b0 = *(const short8*)&wT[(size_t)(0*128 + h*32 + nt*16 + r16)*128 + ks*32 + gq*8];
        short8 b1 = *(const short8*)&wT[(size_t)(1*128 + h*32 + nt*16 + r16)*128 + ks*32 + gq*8];
        short8 b2 = *(const short8*)&wT[(size_t)(2*128 + h*32 + nt*16 + r16)*128 + ks*32 + gq*8];
        short8 b3 = *(const short8*)&wT[(size_t)(3*128 + h*32 + nt*16 + r16)*128 + ks*32 + gq*8];
        #pragma unroll
        for (int mt=0;mt<2;mt++){
          accQ[mt][nt] = __builtin_amdgcn_mfma_f32_16x16x32_bf16(a[mt][ks], b0, accQ[mt][nt], 0,0,0);
          accK[mt][nt] = __builtin_amdgcn_mfma_f32_16x16x32_bf16(a[mt][ks], b1, accK[mt][nt], 0,0,0);
          accV[mt][nt] = __builtin_amdgcn_mfma_f32_16x16x32_bf16(a[mt][ks], b2, accV[mt][nt], 0,0,0);
          accG[mt][nt] = __builtin_amdgcn_mfma_f32_16x16x32_bf16(a[mt][ks], b3, accG[mt][nt], 0,0,0);
        }
      }
    __syncthreads();   // prior head's attention done reading LDS
    #pragma unroll
    for (int mt=0;mt<2;mt++)
      #pragma unroll
      for (int nt=0;nt<2;nt++)
        #pragma unroll
        for (int reg=0;reg<4;reg++){
          int row = w*32+mt*16+gq*4+reg, col = nt*16+r16;
          S[QB_OFF + row*36 + col] = f2bf(accQ[mt][nt][reg]);
          S[KB_OFF + row*36 + col] = f2bf(accK[mt][nt][reg]);
          S[VB_OFF + col*268 + row] = f2bf(accV[mt][nt][reg]);
        }
    __syncthreads();
    // ---- attention phase: wave w handles qt = 2w, 2w+1 (its own GEMM rows) ----
    const u16* ebt = ebx + (size_t)h*16*16*256;
    #pragma unroll
    for (int qs=0; qs<2; qs++){
      const int qt = w*2+qs;
      short8 aq;
      *(short4v*)&aq      = *(const short4v*)&S[QB_OFF + (qt*16+r16)*36 + gq*8];
      *((short4v*)&aq+1)  = *(const short4v*)&S[QB_OFF + (qt*16+r16)*36 + gq*8 + 4];
      float sums[4] = {0.f,0.f,0.f,0.f};
      #pragma unroll
      for (int half=0;half<2;half++){
        f32x4 s[8];
        #pragma unroll
        for (int kt2=0;kt2<8;kt2++){
          int kt = half*8+kt2;
          short8 bk;
          *(short4v*)&bk     = *(const short4v*)&S[KB_OFF + (kt*16+r16)*36 + gq*8];
          *((short4v*)&bk+1) = *(const short4v*)&S[KB_OFF + (kt*16+r16)*36 + gq*8 + 4];
          f32x4 z = {0.f,0.f,0.f,0.f};
          s[kt2] = __builtin_amdgcn_mfma_f32_16x16x32_bf16(aq, bk, z, 0,0,0);
        }
        #pragma unroll
        for (int kt2=0;kt2<8;kt2++){
          int kt = half*8+kt2;
          int kk = kt*16 + r16;
          uint2 er = *(const uint2*)&ebt[((size_t)(qt*16+kt)*64 + lane)*4];
          u16 e4[4]; __builtin_memcpy(e4, &er, 8);
          #pragma unroll
          for (int reg=0;reg<4;reg++){
            float e = __expf(s[kt2][reg]*0.17677669529663687f) * bf2f(e4[reg]) * pm[kt];
            sums[reg] += e;
            Pw[(gq*4+reg)*268 + kk] = f2bf(e);
          }
        }
      }
      #pragma unroll
      for (int reg=0;reg<4;reg++){
        #pragma unroll
        for (int mm=1;mm<=8;mm<<=1) sums[reg] += __shfl_xor(sums[reg],mm,64);
        sums[reg] = 1.f/sums[reg];
      }
      f32x4 o[2]; o[0]=(f32x4){0.f,0.f,0.f,0.f}; o[1]=(f32x4){0.f,0.f,0.f,0.f};
      #pragma unroll
      for (int ks=0;ks<8;ks++){
        short8 ap;
        *(short4v*)&ap     = *(const short4v*)&Pw[r16*268 + ks*32 + gq*8];
        *((short4v*)&ap+1) = *(const short4v*)&Pw[r16*268 + ks*32 + gq*8 + 4];
        #pragma unroll
        for (int ct=0;ct<2;ct++){
          short8 bv;
          *(short4v*)&bv     = *(const short4v*)&S[VB_OFF + (ct*16+r16)*268 + ks*32 + gq*8];
          *((short4v*)&bv+1) = *(const short4v*)&S[VB_OFF + (ct*16+r16)*268 + ks*32 + gq*8 + 4];
          o[ct] = __builtin_amdgcn_mfma_f32_16x16x32_bf16(ap, bv, o[ct], 0,0,0);
        }
      }
      // gate from accG (register-aligned: same C-frag layout) and restage via LDS
      #pragma unroll
      for (int ct=0;ct<2;ct++)
        #pragma unroll
        for (int reg=0;reg<4;reg++){
          float gv = 1.f/(1.f+__expf(-accG[qs][ct][reg]));
          Pw[(gq*4+reg)*40 + ct*16+r16] = f2bf(o[ct][reg]*sums[reg]*gv);
        }
      u32x4 odat = *(const u32x4*)&Pw[(lane>>2)*40 + (lane&3)*8];
      *(u32x4*)&og[((size_t)i*256 + qt*16 + (lane>>2))*128 + h*32 + (lane&3)*8] = odat;
    }
  }
}

// og[65536,128] @ woT + residual -> out; s-pass: + fused e-LN -> zln (transposed); e-pass: transposed scatter
__global__ __launch_bounds__(256) void kproj(const u16* __restrict__ og, const u16* __restrict__ woT,
                                             const float* __restrict__ resid, float* __restrict__ out,
                                             u16* __restrict__ zln, const float* __restrict__ eg,
                                             const float* __restrict__ eb, const int epass){
  const int m0 = blockIdx.x*128;
  __shared__ u16 A[128*136];
  const int tid = threadIdx.x;
  #pragma unroll
  for (int r=0;r<8;r++){
    int chunk = tid + 256*r;
    int row = chunk>>4, off = (chunk&15)*8;
    *(u32x4*)&A[row*136+off] = *(const u32x4*)&og[(size_t)(m0+row)*128+off];
  }
  __syncthreads();
  const int w = tid>>6, lane = tid&63, r16 = lane&15, gq = lane>>4;
  short8 a[2][4];
  #pragma unroll
  for (int mt=0;mt<2;mt++)
    #pragma unroll
    for (int ks=0;ks<4;ks++)
      a[mt][ks] = *(const short8*)&A[(w*32+mt*16+r16)*136 + ks*32 + gq*8];
  f32x4 acc[2][8];
  #pragma unroll
  for (int mt=0;mt<2;mt++)
    #pragma unroll
    for (int nt=0;nt<8;nt++)
      acc[mt][nt] = (f32x4){0.f,0.f,0.f,0.f};
  #pragma unroll
  for (int nt=0;nt<8;nt++){
    short8 bq[4];
    #pragma unroll
    for (int ks=0;ks<4;ks++)
      bq[ks] = *(const short8*)&woT[(size_t)(nt*16+r16)*128 + ks*32 + gq*8];
    #pragma unroll
    for (int mt=0;mt<2;mt++)
      #pragma unroll
      for (int ks=0;ks<4;ks++)
        acc[mt][nt] = __builtin_amdgcn_mfma_f32_16x16x32_bf16(a[mt][ks], bq[ks], acc[mt][nt], 0,0,0);
  }
  if (epass){
    #pragma unroll
    for (int mt=0;mt<2;mt++){
      int mbase = m0+w*32+mt*16+gq*4;
      #pragma unroll
      for (int nt=0;nt<8;nt++){
        int n = nt*16+r16;
        #pragma unroll
        for (int reg=0;reg<4;reg++){
          int m = mbase+reg;
          size_t idx = ((size_t)((m&255)*256+(m>>8)))*128+(size_t)n;
          out[idx] = resid[idx] + acc[mt][nt][reg];
        }
      }
    }
  } else {
    __syncthreads();
    #pragma unroll
    for (int mt=0;mt<2;mt++){
      int mbase = m0+w*32+mt*16+gq*4;
      #pragma unroll
      for (int reg=0;reg<4;reg++){
        int m = mbase+reg;
        float s1 = 0.f, s2 = 0.f;
        #pragma unroll
        for (int nt=0;nt<8;nt++){
          int n = nt*16+r16;
          size_t idx = (size_t)m*128+(size_t)n;
          float v = resid[idx] + acc[mt][nt][reg];
          out[idx] = v;
          acc[mt][nt][reg] = v;
          s1 += v; s2 += v*v;
        }
        #pragma unroll
        for (int mm=1;mm<=8;mm<<=1){ s1 += __shfl_xor(s1,mm,64); s2 += __shfl_xor(s2,mm,64); }
        float mean = s1*(1.f/128.f);
        float rinv = rsqrtf(s2*(1.f/128.f)-mean*mean+1e-5f);
        #pragma unroll
        for (int nt=0;nt<8;nt++){
          int n = nt*16+r16;
          A[(m-m0)*136 + n] = f2bf((acc[mt][nt][reg]-mean)*rinv*eg[n]+eb[n]);
        }
      }
    }
    __syncthreads();
    const int i = m0>>8, jb = m0&255;
    #pragma unroll
    for (int it=0; it<8; it++){
      int chunk = it*256+tid;
      int rl = chunk>>4, c8 = (chunk&15)*8;
      u32x4 vdat = *(const u32x4*)&A[rl*136 + c8];
      *(u32x4*)&zln[((size_t)(jb+rl)*256 + i)*128 + c8] = vdat;
    }
  }
}

extern "C" void kernel_launch(void* const* d_in, const int* in_sizes, int n_in,
                              void* d_out, int out_size, void* d_ws, size_t ws_size,
                              hipStream_t stream) {
  const float* ee     = (const float*)d_in[0];
  const float* coords = (const float*)d_in[1];
  const float* mask   = (const float*)d_in[2];
  const float* w1     = (const float*)d_in[3];
  const float* rg     = (const float*)d_in[4];
  const float* rbta   = (const float*)d_in[5];
  const float* w2     = (const float*)d_in[6];
  const float* g3     = (const float*)d_in[7];
  const float* b3     = (const float*)d_in[8];
  const float* w3     = (const float*)d_in[9];
  const float* sln_g  = (const float*)d_in[10];
  const float* sln_b  = (const float*)d_in[11];
  const float* eln_g  = (const float*)d_in[17];
  const float* eln_b  = (const float*)d_in[18];
  float* out = (float*)d_out;
  char* ws = (char*)d_ws;

  u16*   wT_s  = (u16*)(ws + 0);           // 512x128 bf16
  u16*   wT_e  = (u16*)(ws + 131072);
  u16*   woT_s = (u16*)(ws + 262144);      // 128x128 bf16
  u16*   woT_e = (u16*)(ws + 294912);
  u16*   ebx0  = (u16*)(ws + 327680);      // exp(bias) frag [4][16][16][64][4] bf16
  u16*   ebxT  = (u16*)(ws + 851968);
  float* maskE = (float*)(ws + 1376256);   // transposed mask [256][256] f32
  u16*   zln   = (u16*)(ws + 1638400);     // [65536][128] bf16
  u16*   og    = (u16*)(ws + 18415616);    // [65536][128] bf16 (gated attention out)

  WPtrs wp;
  for (int s=0;s<4;s++){ wp.s[s] = (const float*)d_in[12+s]; wp.d[s] = wT_s + s*128*128; }
  wp.s[4] = (const float*)d_in[16]; wp.d[4] = woT_s;
  for (int s=0;s<4;s++){ wp.s[5+s] = (const float*)d_in[19+s]; wp.d[5+s] = wT_e + s*128*128; }
  wp.s[9] = (const float*)d_in[23]; wp.d[9] = woT_e;
  kconv_all<<<640,256,0,stream>>>(wp);

  kprep<<<16384,256,0,stream>>>(ee, coords, w1, rg, rbta, w2, g3, b3, w3, sln_g, sln_b,
                                mask, zln, ebx0, ebxT, maskE);

  // ---- starting pass ----
  kfused<<<256,512,0,stream>>>(zln, wT_s, ebx0, mask, og);
  kproj<<<512,256,0,stream>>>(og, woT_s, ee, out, zln, eln_g, eln_b, 0);

  // ---- ending pass (transposed frame; zln = e-LN'd transposed, from kproj) ----
  kfused<<<256,512,0,stream>>>(zln, wT_e, ebxT, maskE, og);
  kproj<<<512,256,0,stream>>>(og, woT_e, out, out, nullptr, nullptr, nullptr, 1);
}

// Round 8
// 392.740 us; speedup vs baseline: 1.4042x; 1.1167x over previous
//
#include <hip/hip_runtime.h>

typedef unsigned short u16;
typedef unsigned int u32;
typedef __attribute__((ext_vector_type(8))) short short8;
typedef __attribute__((ext_vector_type(4))) float f32x4;
typedef __attribute__((ext_vector_type(4))) u32 u32x4;

__device__ __forceinline__ float bf2f(u16 u){ u32 x = ((u32)u)<<16; float f; __builtin_memcpy(&f,&x,4); return f; }
__device__ __forceinline__ u16 f2bf(float f){ u32 u; __builtin_memcpy(&u,&f,4); u32 r = (u + 0x7fffu + ((u>>16)&1u))>>16; return (u16)r; }

__device__ __forceinline__ float wsum64(float v){
  #pragma unroll
  for (int m=32;m>=1;m>>=1) v += __shfl_xor(v,m,64);
  return v;
}
__device__ __forceinline__ float wsum32(float v){
  #pragma unroll
  for (int m=16;m>=1;m>>=1) v += __shfl_xor(v,m,64);
  return v;
}

struct WPtrs { const float* s[10]; u16* d[10]; };

__global__ __launch_bounds__(256) void kconv_all(WPtrs wp){
  int mid = blockIdx.x>>6;
  int t = (blockIdx.x&63)*256 + threadIdx.x;
  int n = t>>7, k = t&127;
  wp.d[mid][n*128+k] = f2bf(wp.s[mid][k*128+n]);
}

// one wave per pair (i,j): dist->rbf->LN->dist_bias; shared edge LN -> zln + exp(bias) in C-frag layout
__global__ __launch_bounds__(256) void kprep(
    const float* __restrict__ ee, const float* __restrict__ coords,
    const float* __restrict__ w1, const float* __restrict__ rg, const float* __restrict__ rbta,
    const float* __restrict__ w2, const float* __restrict__ g3, const float* __restrict__ b3,
    const float* __restrict__ w3, const float* __restrict__ gs, const float* __restrict__ bs,
    const float* __restrict__ mask,
    u16* __restrict__ zln, u16* __restrict__ ebx0, u16* __restrict__ ebxT,
    float* __restrict__ maskE)
{
  int wid = (blockIdx.x*256 + threadIdx.x)>>6;
  int lane = threadIdx.x & 63;
  int i = wid>>8, j = wid&255;
  float dx = coords[i*3+0]-coords[j*3+0];
  float dy = coords[i*3+1]-coords[j*3+1];
  float dz = coords[i*3+2]-coords[j*3+2];
  float dist = sqrtf(dx*dx+dy*dy+dz*dz+1e-12f);
  int c = lane&31;
  // per-lane RBF (dist is wave-uniform): no cross-lane chain
  float hacc0 = 0.f, hacc1 = 0.f;
  #pragma unroll
  for (int r=0;r<39;r+=2){
    float t0 = (dist-(0.325f+0.125f*(float)r))*8.210526315789474f;
    hacc0 = fmaf(__expf(-t0*t0), w1[r*32+c], hacc0);
    if (r+1<39){
      float t1 = (dist-(0.325f+0.125f*(float)(r+1)))*8.210526315789474f;
      hacc1 = fmaf(__expf(-t1*t1), w1[(r+1)*32+c], hacc1);
    }
  }
  float hacc = hacc0 + hacc1;
  float mu = wsum32(hacc)*(1.f/32.f);
  float vr = wsum32(hacc*hacc)*(1.f/32.f) - mu*mu;
  float hn = (hacc-mu)*rsqrtf(vr+1e-5f)*rg[c]+rbta[c];
  float db0 = wsum32(hn*w2[c*4+0]);
  float db1 = wsum32(hn*w2[c*4+1]);
  float db2 = wsum32(hn*w2[c*4+2]);
  float db3 = wsum32(hn*w2[c*4+3]);
  int c0 = lane*2, c1 = lane*2+1;
  float x0 = ee[(size_t)wid*128+c0], x1 = ee[(size_t)wid*128+c1];
  float m2 = wsum64(x0+x1)*(1.f/128.f);
  float v2 = wsum64(x0*x0+x1*x1)*(1.f/128.f)-m2*m2;
  float rinv = rsqrtf(v2+1e-5f);
  float n0 = (x0-m2)*rinv, n1 = (x1-m2)*rinv;
  u32 pk = (u32)f2bf(n0*gs[c0]+bs[c0]) | ((u32)f2bf(n1*gs[c1]+bs[c1])<<16);
  ((u32*)zln)[(size_t)wid*64+lane] = pk;
  float t0 = n0*g3[c0]+b3[c0], t1 = n1*g3[c1]+b3[c1];
  float th0 = wsum64(t0*w3[c0*4+0]+t1*w3[c1*4+0]);
  float th1 = wsum64(t0*w3[c0*4+1]+t1*w3[c1*4+1]);
  float th2 = wsum64(t0*w3[c0*4+2]+t1*w3[c1*4+2]);
  float th3 = wsum64(t0*w3[c0*4+3]+t1*w3[c1*4+3]);
  if (lane<4){
    float v = (lane==0)?(db0+th0):(lane==1)?(db1+th1):(lane==2)?(db2+th2):(db3+th3);
    u16 ev = f2bf(__expf(v));
    int h = lane;
    ebx0[(((size_t)(h*16+(i>>4))*16+(j>>4))*256) + ((j&15)+((i>>2)&3)*16)*4 + (i&3)] = ev;
    ebxT[(((size_t)(h*16+(j>>4))*16+(i>>4))*256) + ((i&15)+((j>>2)&3)*16)*4 + (j&3)] = ev;
  }
  if (lane==4) maskE[(size_t)j*256+i] = mask[(size_t)wid];
}

// ---- fused QKVG-GEMM + attention + gate: block=(i,h), 256 thr (4 waves), LDS 80KB = 2 blocks/CU ----
// u16 offsets: QS=0 (16 qt x 512), KS=8192, VS=16384, PS=24576 + w*4096 (swizzled 16x256)
#define QS 0
#define KS 8192
#define VS 16384
#define PS 24576
__global__ __launch_bounds__(256,2) void kfused(const u16* __restrict__ zln, const u16* __restrict__ wT,
                                                const u16* __restrict__ ebx, const float* __restrict__ maskp,
                                                u16* __restrict__ og){
  __shared__ u16 S[40960];
  const int i = blockIdx.x, h = blockIdx.y, tid = threadIdx.x;
  const int w = tid>>6, lane = tid&63, r16 = lane&15, gq = lane>>4;
  // A-fragments straight from global (z-slice is L2-hot: 64KB shared by 4 head-blocks)
  short8 a[4][4];
  const u16* zb = zln + (size_t)i*32768;
  #pragma unroll
  for (int mt=0;mt<4;mt++)
    #pragma unroll
    for (int ks=0;ks<4;ks++)
      a[mt][ks] = *(const short8*)&zb[(w*64 + mt*16 + r16)*128 + ks*32 + gq*8];
  float pm[16];
  const float* mrow = maskp + (size_t)i*256;
  #pragma unroll
  for (int kt=0;kt<16;kt++)
    pm[kt] = (mrow[kt*16+r16] > 0.999f) ? 1.f : 0.f;

  // ---- GEMM: Q,K,V to LDS (frag layout), G kept in registers ----
  f32x4 accG[4][2];
  #pragma unroll
  for (int sel=0; sel<4; sel++){
    f32x4 acc[4][2];
    #pragma unroll
    for (int mt=0;mt<4;mt++){ acc[mt][0]=(f32x4){0,0,0,0}; acc[mt][1]=(f32x4){0,0,0,0}; }
    #pragma unroll
    for (int nt=0;nt<2;nt++)
      #pragma unroll
      for (int ks=0;ks<4;ks++){
        short8 bq = *(const short8*)&wT[((size_t)sel*128 + h*32 + nt*16 + r16)*128 + ks*32 + gq*8];
        #pragma unroll
        for (int mt=0;mt<4;mt++)
          acc[mt][nt] = __builtin_amdgcn_mfma_f32_16x16x32_bf16(a[mt][ks], bq, acc[mt][nt], 0,0,0);
      }
    if (sel==3){
      #pragma unroll
      for (int mt=0;mt<4;mt++){ accG[mt][0]=acc[mt][0]; accG[mt][1]=acc[mt][1]; }
    } else {
      #pragma unroll
      for (int mt=0;mt<4;mt++)
        #pragma unroll
        for (int nt=0;nt<2;nt++)
          #pragma unroll
          for (int reg=0;reg<4;reg++){
            int row = w*64 + mt*16 + gq*4 + reg;      // 0..255
            int c   = nt*16 + r16;                    // 0..31
            u16 v = f2bf(acc[mt][nt][reg]);
            if (sel==0)      S[QS + (row>>4)*512 + (row&15)*8 + (c>>3)*128 + (c&7)] = v;
            else if (sel==1) S[KS + (row>>4)*512 + (row&15)*8 + (c>>3)*128 + (c&7)] = v;
            else             S[VS + ((row>>5)*2 + nt)*512 + ((c&15) + ((row&31)>>3)*16)*8 + (row&7)] = v;
          }
    }
  }
  __syncthreads();   // the only block-wide barrier

  // ---- attention: wave w owns qt = w*4..w*4+3 (its own GEMM rows; accG aligned) ----
  const u16* ebt = ebx + (size_t)h*16*16*256;
  char* Pb = (char*)&S[PS + w*4096];
  for (int qs=0; qs<4; qs++){
    const int qt = w*4+qs;
    short8 aq = *(const short8*)&S[QS + qt*512 + lane*8];
    float sums[4] = {0.f,0.f,0.f,0.f};
    #pragma unroll
    for (int half=0;half<2;half++){
      f32x4 s[8];
      #pragma unroll
      for (int kt2=0;kt2<8;kt2++){
        short8 bk = *(const short8*)&S[KS + (half*8+kt2)*512 + lane*8];
        f32x4 z = {0.f,0.f,0.f,0.f};
        s[kt2] = __builtin_amdgcn_mfma_f32_16x16x32_bf16(aq, bk, z, 0,0,0);
      }
      #pragma unroll
      for (int kt2=0;kt2<8;kt2++){
        int kt = half*8+kt2;
        int kk = kt*16 + r16;
        uint2 er = *(const uint2*)&ebt[((size_t)(qt*16+kt)*64 + lane)*4];
        u16 e4[4]; __builtin_memcpy(e4, &er, 8);
        #pragma unroll
        for (int reg=0;reg<4;reg++){
          float e = __expf(s[kt2][reg]*0.17677669529663687f) * bf2f(e4[reg]) * pm[kt];
          sums[reg] += e;
          int row = gq*4+reg;
          *(u16*)(Pb + ((row*512 + kk*2) ^ ((row&7)<<4))) = f2bf(e);
        }
      }
    }
    #pragma unroll
    for (int reg=0;reg<4;reg++){
      #pragma unroll
      for (int mm=1;mm<=8;mm<<=1) sums[reg] += __shfl_xor(sums[reg],mm,64);
      sums[reg] = 1.f/sums[reg];
    }
    f32x4 o[2]; o[0]=(f32x4){0.f,0.f,0.f,0.f}; o[1]=(f32x4){0.f,0.f,0.f,0.f};
    #pragma unroll
    for (int ks=0;ks<8;ks++){
      short8 ap = *(const short8*)(Pb + ((r16*512 + ks*64 + gq*16) ^ ((r16&7)<<4)));
      #pragma unroll
      for (int ct=0;ct<2;ct++){
        short8 bv = *(const short8*)&S[VS + (ks*2+ct)*512 + lane*8];
        o[ct] = __builtin_amdgcn_mfma_f32_16x16x32_bf16(ap, bv, o[ct], 0,0,0);
      }
    }
    // gate from accG (register-aligned) + restage via own P area -> 16B coalesced og stores
    u16* Ob = (u16*)Pb;
    #pragma unroll
    for (int ct=0;ct<2;ct++)
      #pragma unroll
      for (int reg=0;reg<4;reg++){
        float gv = 1.f/(1.f+__expf(-accG[qs][ct][reg]));
        Ob[(gq*4+reg)*40 + ct*16+r16] = f2bf(o[ct][reg]*sums[reg]*gv);
      }
    u32x4 odat = *(const u32x4*)&Ob[(lane>>2)*40 + (lane&3)*8];
    *(u32x4*)&og[((size_t)i*256 + qt*16 + (lane>>2))*128 + h*32 + (lane&3)*8] = odat;
  }
}

// og[65536,128] @ woT + residual -> out; s-pass: + fused e-LN -> zln (transposed); e-pass: transposed scatter
__global__ __launch_bounds__(256) void kproj(const u16* __restrict__ og, const u16* __restrict__ woT,
                                             const float* __restrict__ resid, float* __restrict__ out,
                                             u16* __restrict__ zln, const float* __restrict__ eg,
                                             const float* __restrict__ eb, const int epass){
  const int m0 = blockIdx.x*128;
  __shared__ u16 A[128*136];
  const int tid = threadIdx.x;
  #pragma unroll
  for (int r=0;r<8;r++){
    int chunk = tid + 256*r;
    int row = chunk>>4, off = (chunk&15)*8;
    *(u32x4*)&A[row*136+off] = *(const u32x4*)&og[(size_t)(m0+row)*128+off];
  }
  __syncthreads();
  const int w = tid>>6, lane = tid&63, r16 = lane&15, gq = lane>>4;
  short8 a[2][4];
  #pragma unroll
  for (int mt=0;mt<2;mt++)
    #pragma unroll
    for (int ks=0;ks<4;ks++)
      a[mt][ks] = *(const short8*)&A[(w*32+mt*16+r16)*136 + ks*32 + gq*8];
  f32x4 acc[2][8];
  #pragma unroll
  for (int mt=0;mt<2;mt++)
    #pragma unroll
    for (int nt=0;nt<8;nt++)
      acc[mt][nt] = (f32x4){0.f,0.f,0.f,0.f};
  #pragma unroll
  for (int nt=0;nt<8;nt++){
    short8 bq[4];
    #pragma unroll
    for (int ks=0;ks<4;ks++)
      bq[ks] = *(const short8*)&woT[(size_t)(nt*16+r16)*128 + ks*32 + gq*8];
    #pragma unroll
    for (int mt=0;mt<2;mt++)
      #pragma unroll
      for (int ks=0;ks<4;ks++)
        acc[mt][nt] = __builtin_amdgcn_mfma_f32_16x16x32_bf16(a[mt][ks], bq[ks], acc[mt][nt], 0,0,0);
  }
  if (epass){
    #pragma unroll
    for (int mt=0;mt<2;mt++){
      int mbase = m0+w*32+mt*16+gq*4;
      #pragma unroll
      for (int nt=0;nt<8;nt++){
        int n = nt*16+r16;
        #pragma unroll
        for (int reg=0;reg<4;reg++){
          int m = mbase+reg;
          size_t idx = ((size_t)((m&255)*256+(m>>8)))*128+(size_t)n;
          out[idx] = resid[idx] + acc[mt][nt][reg];
        }
      }
    }
  } else {
    __syncthreads();
    #pragma unroll
    for (int mt=0;mt<2;mt++){
      int mbase = m0+w*32+mt*16+gq*4;
      #pragma unroll
      for (int reg=0;reg<4;reg++){
        int m = mbase+reg;
        float s1 = 0.f, s2 = 0.f;
        #pragma unroll
        for (int nt=0;nt<8;nt++){
          int n = nt*16+r16;
          size_t idx = (size_t)m*128+(size_t)n;
          float v = resid[idx] + acc[mt][nt][reg];
          out[idx] = v;
          acc[mt][nt][reg] = v;
          s1 += v; s2 += v*v;
        }
        #pragma unroll
        for (int mm=1;mm<=8;mm<<=1){ s1 += __shfl_xor(s1,mm,64); s2 += __shfl_xor(s2,mm,64); }
        float mean = s1*(1.f/128.f);
        float rinv = rsqrtf(s2*(1.f/128.f)-mean*mean+1e-5f);
        #pragma unroll
        for (int nt=0;nt<8;nt++){
          int n = nt*16+r16;
          A[(m-m0)*136 + n] = f2bf((acc[mt][nt][reg]-mean)*rinv*eg[n]+eb[n]);
        }
      }
    }
    __syncthreads();
    const int i = m0>>8, jb = m0&255;
    #pragma unroll
    for (int it=0; it<8; it++){
      int chunk = it*256+tid;
      int rl = chunk>>4, c8 = (chunk&15)*8;
      u32x4 vdat = *(const u32x4*)&A[rl*136 + c8];
      *(u32x4*)&zln[((size_t)(jb+rl)*256 + i)*128 + c8] = vdat;
    }
  }
}

extern "C" void kernel_launch(void* const* d_in, const int* in_sizes, int n_in,
                              void* d_out, int out_size, void* d_ws, size_t ws_size,
                              hipStream_t stream) {
  const float* ee     = (const float*)d_in[0];
  const float* coords = (const float*)d_in[1];
  const float* mask   = (const float*)d_in[2];
  const float* w1     = (const float*)d_in[3];
  const float* rg     = (const float*)d_in[4];
  const float* rbta   = (const float*)d_in[5];
  const float* w2     = (const float*)d_in[6];
  const float* g3     = (const float*)d_in[7];
  const float* b3     = (const float*)d_in[8];
  const float* w3     = (const float*)d_in[9];
  const float* sln_g  = (const float*)d_in[10];
  const float* sln_b  = (const float*)d_in[11];
  const float* eln_g  = (const float*)d_in[17];
  const float* eln_b  = (const float*)d_in[18];
  float* out = (float*)d_out;
  char* ws = (char*)d_ws;

  u16*   wT_s  = (u16*)(ws + 0);           // 512x128 bf16
  u16*   wT_e  = (u16*)(ws + 131072);
  u16*   woT_s = (u16*)(ws + 262144);      // 128x128 bf16
  u16*   woT_e = (u16*)(ws + 294912);
  u16*   ebx0  = (u16*)(ws + 327680);      // exp(bias) frag [4][16][16][64][4] bf16
  u16*   ebxT  = (u16*)(ws + 851968);
  float* maskE = (float*)(ws + 1376256);   // transposed mask [256][256] f32
  u16*   zln   = (u16*)(ws + 1638400);     // [65536][128] bf16
  u16*   og    = (u16*)(ws + 18415616);    // [65536][128] bf16 (gated attention out)

  WPtrs wp;
  for (int s=0;s<4;s++){ wp.s[s] = (const float*)d_in[12+s]; wp.d[s] = wT_s + s*128*128; }
  wp.s[4] = (const float*)d_in[16]; wp.d[4] = woT_s;
  for (int s=0;s<4;s++){ wp.s[5+s] = (const float*)d_in[19+s]; wp.d[5+s] = wT_e + s*128*128; }
  wp.s[9] = (const float*)d_in[23]; wp.d[9] = woT_e;
  kconv_all<<<640,256,0,stream>>>(wp);

  kprep<<<16384,256,0,stream>>>(ee, coords, w1, rg, rbta, w2, g3, b3, w3, sln_g, sln_b,
                                mask, zln, ebx0, ebxT, maskE);

  // ---- starting pass ----
  kfused<<<dim3(256,4),256,0,stream>>>(zln, wT_s, ebx0, mask, og);
  kproj<<<512,256,0,stream>>>(og, woT_s, ee, out, zln, eln_g, eln_b, 0);

  // ---- ending pass (transposed frame; zln = e-LN'd transposed, from kproj) ----
  kfused<<<dim3(256,4),256,0,stream>>>(zln, wT_e, ebxT, maskE, og);
  kproj<<<512,256,0,stream>>>(og, woT_e, out, out, nullptr, nullptr, nullptr, 1);
}